// Round 2
// baseline (503.761 us; speedup 1.0000x reference)
//
#include <hip/hip_runtime.h>
#include <math.h>

#define L_SEQ 384
#define E_DIM 512
#define NHEAD 8
#define NBH   16
#define HD    64
#define JSPLIT 12
#define JTILE  32          // L_SEQ / JSPLIT
#define PROJ_ELEMS (NBH * L_SEQ * HD)   // 393216

__device__ __forceinline__ float uniform_f(float v) {
  return __uint_as_float(__builtin_amdgcn_readfirstlane(__float_as_uint(v)));
}

// ---------------------------------------------------------------------------
// Split-K GEMM: C += A[:, kc*kchunk : (kc+1)*kchunk] @ Bm^T (atomicAdd epi).
// A: MxK row-major, Bm: NxK row-major. grid.z = mat*nkc + kc.
// mode 0: C[m*N + f]; mode 1: head-scatter C[((b*8+h)*L + l)*64 + d].
// Tile 64x64, BK=16, 256 threads, 4x4 per thread.
// ---------------------------------------------------------------------------
__global__ __launch_bounds__(256) void gemm_abt_splitk(
    const float* __restrict__ A, const float* __restrict__ B0,
    const float* __restrict__ B1, const float* __restrict__ B2,
    float* __restrict__ C0, float* __restrict__ C1, float* __restrict__ C2,
    int M, int N, int K, int kchunk, int nkc, int mode)
{
  __shared__ float As[16][68];
  __shared__ float Bs[16][68];

  const int tid = threadIdx.x;
  const int z = blockIdx.z;
  const int mat = z / nkc, kc = z - mat * nkc;
  const float* Bm = (mat == 0) ? B0 : (mat == 1) ? B1 : B2;
  float* Cp = (mat == 0) ? C0 : (mat == 1) ? C1 : C2;

  const int m0 = blockIdx.y * 64;
  const int n0 = blockIdx.x * 64;
  const int tm = tid >> 4;
  const int tn = tid & 15;

  float acc[4][4];
  #pragma unroll
  for (int r = 0; r < 4; ++r)
    #pragma unroll
    for (int c = 0; c < 4; ++c) acc[r][c] = 0.f;

  const int kbeg = kc * kchunk, kend = kbeg + kchunk;
  for (int k0 = kbeg; k0 < kend; k0 += 16) {
    #pragma unroll
    for (int p = 0; p < 4; ++p) {
      int idx = tid + p * 256;
      int row = idx >> 4, col = idx & 15;
      As[col][row] = A[(size_t)(m0 + row) * K + k0 + col];
      Bs[col][row] = Bm[(size_t)(n0 + row) * K + k0 + col];
    }
    __syncthreads();
    #pragma unroll
    for (int kk = 0; kk < 16; ++kk) {
      float4 a = *(const float4*)&As[kk][tm * 4];
      float4 b = *(const float4*)&Bs[kk][tn * 4];
      float av[4] = {a.x, a.y, a.z, a.w};
      float bv[4] = {b.x, b.y, b.z, b.w};
      #pragma unroll
      for (int r = 0; r < 4; ++r)
        #pragma unroll
        for (int c = 0; c < 4; ++c) acc[r][c] += av[r] * bv[c];
    }
    __syncthreads();
  }

  #pragma unroll
  for (int r = 0; r < 4; ++r) {
    int m = m0 + tm * 4 + r;
    int f0 = n0 + tn * 4;
    float* dst;
    if (mode == 0) {
      dst = &Cp[(size_t)m * N + f0];
    } else {
      int b = m / L_SEQ, l = m % L_SEQ;
      int h = f0 >> 6, d = f0 & 63;
      dst = &Cp[((size_t)(b * NHEAD + h) * L_SEQ + l) * HD + d];
    }
    atomicAdd(dst + 0, acc[r][0]);
    atomicAdd(dst + 1, acc[r][1]);
    atomicAdd(dst + 2, acc[r][2]);
    atomicAdd(dst + 3, acc[r][3]);
  }
}

// ---------------------------------------------------------------------------
// Fused pairwise core v2.
// Grid (JSPLIT=12, 6, 16), block 256 = 64 i x 4 atom-groups; 32 j per block.
// Strength reduction: |ham(q,k)| = |q|*|k| -> precompute rsq norms.
// Output: per-jsplit slab (plain float4 stores, no atomics).
// ---------------------------------------------------------------------------
__global__ __launch_bounds__(256, 6) void berry_main(
    const float* __restrict__ Q, const float* __restrict__ K,
    const float* __restrict__ V, const float* __restrict__ dde_w,
    const float* __restrict__ dde_b, float* __restrict__ CTXS)
{
  __shared__ float kt[JTILE][HD];
  __shared__ float vt[JTILE][HD];
  __shared__ float ivk[JTILE][16];

  const int tid = threadIdx.x;
  const int bh = blockIdx.z;
  const int i = blockIdx.y * 64 + (tid >> 2);
  const int ag = tid & 3;
  const int js = blockIdx.x;
  const int j0 = js * JTILE;

  // gate params in SGPRs; mean over 16 atoms folded into weights
  float gw[16];
  #pragma unroll
  for (int t = 0; t < 16; ++t) gw[t] = uniform_f(dde_w[t]) * 0.0625f;
  const float gb0 = uniform_f(dde_b[0]), gb1 = uniform_f(dde_b[1]);
  const float gb2 = uniform_f(dde_b[2]), gb3 = uniform_f(dde_b[3]);

  float4 qa[4], ctx[4];
  float ivq[4];
  const float* qp = Q + ((size_t)(bh * L_SEQ + i) * HD + ag * 16);
  #pragma unroll
  for (int t = 0; t < 4; ++t) {
    qa[t] = ((const float4*)qp)[t];
    float d = qa[t].x * qa[t].x + qa[t].y * qa[t].y +
              qa[t].z * qa[t].z + qa[t].w * qa[t].w;
    ivq[t] = __builtin_amdgcn_rsqf(fmaxf(d, 1e-30f));
    ctx[t] = make_float4(0.f, 0.f, 0.f, 0.f);
  }

  // stage K/V tile (32 j x 64 floats each)
  #pragma unroll
  for (int p = 0; p < 2; ++p) {
    int idx = tid + p * 256;           // 0..511 = 32 j x 16 float4
    int jj = idx >> 4, fq = (idx & 15) * 4;
    size_t g = (size_t)(bh * L_SEQ + j0 + jj) * HD + fq;
    *(float4*)&kt[jj][fq] = *(const float4*)(K + g);
    *(float4*)&vt[jj][fq] = *(const float4*)(V + g);
  }
  __syncthreads();
  // per-(j, atom) inverse k-norms: 512 atoms, 2 per thread
  #pragma unroll
  for (int p = 0; p < 2; ++p) {
    int a = tid + p * 256;
    int jj = a >> 4, at = a & 15;
    float4 kq = *(const float4*)&kt[jj][at * 4];
    float d = kq.x * kq.x + kq.y * kq.y + kq.z * kq.z + kq.w * kq.w;
    ivk[jj][at] = __builtin_amdgcn_rsqf(fmaxf(d, 1e-30f));
  }
  __syncthreads();

  for (int jj = 0; jj < JTILE; ++jj) {
    float4 sp[4];
    float4 ik4 = *(const float4*)&ivk[jj][ag * 4];
    float ikv[4] = {ik4.x, ik4.y, ik4.z, ik4.w};
    float4 gs = make_float4(0.f, 0.f, 0.f, 0.f);
    #pragma unroll
    for (int a = 0; a < 4; ++a) {
      float4 kq = *(const float4*)&kt[jj][ag * 16 + a * 4];
      float inv = ivq[a] * ikv[a];
      float hx = qa[a].x * kq.x - qa[a].y * kq.y - qa[a].z * kq.z - qa[a].w * kq.w;
      float hy = qa[a].x * kq.y + qa[a].y * kq.x + qa[a].z * kq.w - qa[a].w * kq.z;
      float hz = qa[a].x * kq.z - qa[a].y * kq.w + qa[a].z * kq.x + qa[a].w * kq.y;
      float hw = qa[a].x * kq.w + qa[a].y * kq.z - qa[a].z * kq.y + qa[a].w * kq.x;
      sp[a].x = hx * inv; sp[a].y = hy * inv;
      sp[a].z = hz * inv; sp[a].w = hw * inv;
      gs.x += sp[a].x; gs.y += sp[a].y; gs.z += sp[a].z; gs.w += sp[a].w;
    }
    // sum across the 4 atom-group lanes (16 atoms); mean folded into gw
    gs.x += __shfl_xor(gs.x, 1, 64); gs.y += __shfl_xor(gs.y, 1, 64);
    gs.z += __shfl_xor(gs.z, 1, 64); gs.w += __shfl_xor(gs.w, 1, 64);
    gs.x += __shfl_xor(gs.x, 2, 64); gs.y += __shfl_xor(gs.y, 2, 64);
    gs.z += __shfl_xor(gs.z, 2, 64); gs.w += __shfl_xor(gs.w, 2, 64);

    float t0 = gb0 + gw[0]  * gs.x + gw[1]  * gs.y + gw[2]  * gs.z + gw[3]  * gs.w;
    float t1 = gb1 + gw[4]  * gs.x + gw[5]  * gs.y + gw[6]  * gs.z + gw[7]  * gs.w;
    float t2 = gb2 + gw[8]  * gs.x + gw[9]  * gs.y + gw[10] * gs.z + gw[11] * gs.w;
    float t3 = gb3 + gw[12] * gs.x + gw[13] * gs.y + gw[14] * gs.z + gw[15] * gs.w;
    float4 g;
    g.x = __builtin_amdgcn_rcpf(1.f + __expf(-t0));
    g.y = __builtin_amdgcn_rcpf(1.f + __expf(-t1));
    g.z = __builtin_amdgcn_rcpf(1.f + __expf(-t2));
    g.w = __builtin_amdgcn_rcpf(1.f + __expf(-t3));

    #pragma unroll
    for (int a = 0; a < 4; ++a) {
      float4 vq = *(const float4*)&vt[jj][ag * 16 + a * 4];
      float sx = sp[a].x * g.x, sy = sp[a].y * g.y;
      float sz = sp[a].z * g.z, sw = sp[a].w * g.w;
      ctx[a].x += sx * vq.x - sy * vq.y - sz * vq.z - sw * vq.w;
      ctx[a].y += sx * vq.y + sy * vq.x + sz * vq.w - sw * vq.z;
      ctx[a].z += sx * vq.z - sy * vq.w + sz * vq.x + sw * vq.y;
      ctx[a].w += sx * vq.w + sy * vq.z - sz * vq.y + sw * vq.x;
    }
  }

  // plain stores into this j-chunk's slab
  float* cp = CTXS + ((size_t)(js * NBH + bh) * L_SEQ + i) * HD + ag * 16;
  #pragma unroll
  for (int t = 0; t < 4; ++t) ((float4*)cp)[t] = ctx[t];
}

// ---------------------------------------------------------------------------
// Sum the JSPLIT ctx slabs and transpose heads into (b, l, e) layout.
// ---------------------------------------------------------------------------
__global__ __launch_bounds__(256) void ctx_reduce(
    const float* __restrict__ CTXS, float* __restrict__ CTX)
{
  int idx = blockIdx.x * 256 + threadIdx.x;      // over 98304 float4 groups
  int row = idx >> 4;                            // bh*L + i
  int d0 = (idx & 15) * 4;
  float4 s = make_float4(0.f, 0.f, 0.f, 0.f);
  #pragma unroll
  for (int js = 0; js < JSPLIT; ++js) {
    float4 v = *(const float4*)&CTXS[(size_t)js * PROJ_ELEMS + (size_t)row * HD + d0];
    s.x += v.x; s.y += v.y; s.z += v.z; s.w += v.w;
  }
  int bh = row / L_SEQ, i = row - bh * L_SEQ;
  int b = bh >> 3, h = bh & 7;
  *(float4*)&CTX[((size_t)(b * L_SEQ + i) * E_DIM) + h * HD + d0] = s;
}

// ---------------------------------------------------------------------------
extern "C" void kernel_launch(void* const* d_in, const int* in_sizes, int n_in,
                              void* d_out, int out_size, void* d_ws, size_t ws_size,
                              hipStream_t stream)
{
  const float* x     = (const float*)d_in[0];
  const float* Wq    = (const float*)d_in[1];
  const float* Wk    = (const float*)d_in[2];
  const float* Wv    = (const float*)d_in[3];
  const float* Wo    = (const float*)d_in[4];
  const float* dde_w = (const float*)d_in[5];
  const float* dde_b = (const float*)d_in[6];
  float* out = (float*)d_out;

  float* Qw   = (float*)d_ws;
  float* Kw   = Qw + PROJ_ELEMS;
  float* Vw   = Kw + PROJ_ELEMS;
  float* CTX  = Vw + PROJ_ELEMS;
  float* CTXS = CTX + PROJ_ELEMS;                // JSPLIT slabs

  // zero atomic-accumulated outputs (Qw/Kw/Vw contiguous) and d_out
  hipMemsetAsync(Qw, 0, (size_t)3 * PROJ_ELEMS * sizeof(float), stream);
  hipMemsetAsync(out, 0, (size_t)2 * L_SEQ * E_DIM * sizeof(float), stream);

  // Q/K/V projections: split-K=4, head-scatter epilogue
  dim3 gp(E_DIM / 64, (2 * L_SEQ) / 64, 3 * 4);
  gemm_abt_splitk<<<gp, 256, 0, stream>>>(x, Wq, Wk, Wv, Qw, Kw, Vw,
                                          2 * L_SEQ, E_DIM, E_DIM, 128, 4, 1);

  // fused pairwise core
  dim3 gm(JSPLIT, 6, NBH);
  berry_main<<<gm, 256, 0, stream>>>(Qw, Kw, Vw, dde_w, dde_b, CTXS);

  // slab reduction + head transpose
  ctx_reduce<<<384, 256, 0, stream>>>(CTXS, CTX);

  // output projection: split-K=4
  dim3 go(E_DIM / 64, (2 * L_SEQ) / 64, 4);
  gemm_abt_splitk<<<go, 256, 0, stream>>>(CTX, Wo, nullptr, nullptr, out, nullptr, nullptr,
                                          2 * L_SEQ, E_DIM, E_DIM, 128, 4, 0);
}

// Round 3
// 252.102 us; speedup vs baseline: 1.9982x; 1.9982x over previous
//
#include <hip/hip_runtime.h>
#include <math.h>

#define L_SEQ 384
#define E_DIM 512
#define NHEAD 8
#define NBH   16
#define HD    64
#define JSPLIT 12
#define JTILE  32          // L_SEQ / JSPLIT
#define PROJ_ELEMS (NBH * L_SEQ * HD)   // 393216

__device__ __forceinline__ float uniform_f(float v) {
  return __uint_as_float(__builtin_amdgcn_readfirstlane(__float_as_uint(v)));
}

// ---------------------------------------------------------------------------
// Split-K GEMM: C += A[:, kc*kchunk : (kc+1)*kchunk] @ Bm^T (atomicAdd epi).
// A: MxK row-major, Bm: NxK row-major. grid.z = mat*nkc + kc.
// mode 0: C[m*N + f]; mode 1: head-scatter C[((b*8+h)*L + l)*64 + d].
// Tile 64x64, BK=16, 256 threads, 4x4 per thread.
// ---------------------------------------------------------------------------
__global__ __launch_bounds__(256) void gemm_abt_splitk(
    const float* __restrict__ A, const float* __restrict__ B0,
    const float* __restrict__ B1, const float* __restrict__ B2,
    float* __restrict__ C0, float* __restrict__ C1, float* __restrict__ C2,
    int M, int N, int K, int kchunk, int nkc, int mode)
{
  __shared__ float As[16][68];
  __shared__ float Bs[16][68];

  const int tid = threadIdx.x;
  const int z = blockIdx.z;
  const int mat = z / nkc, kc = z - mat * nkc;
  const float* Bm = (mat == 0) ? B0 : (mat == 1) ? B1 : B2;
  float* Cp = (mat == 0) ? C0 : (mat == 1) ? C1 : C2;

  const int m0 = blockIdx.y * 64;
  const int n0 = blockIdx.x * 64;
  const int tm = tid >> 4;
  const int tn = tid & 15;

  float acc[4][4];
  #pragma unroll
  for (int r = 0; r < 4; ++r)
    #pragma unroll
    for (int c = 0; c < 4; ++c) acc[r][c] = 0.f;

  const int kbeg = kc * kchunk, kend = kbeg + kchunk;
  for (int k0 = kbeg; k0 < kend; k0 += 16) {
    #pragma unroll
    for (int p = 0; p < 4; ++p) {
      int idx = tid + p * 256;
      int row = idx >> 4, col = idx & 15;
      As[col][row] = A[(size_t)(m0 + row) * K + k0 + col];
      Bs[col][row] = Bm[(size_t)(n0 + row) * K + k0 + col];
    }
    __syncthreads();
    #pragma unroll
    for (int kk = 0; kk < 16; ++kk) {
      float4 a = *(const float4*)&As[kk][tm * 4];
      float4 b = *(const float4*)&Bs[kk][tn * 4];
      float av[4] = {a.x, a.y, a.z, a.w};
      float bv[4] = {b.x, b.y, b.z, b.w};
      #pragma unroll
      for (int r = 0; r < 4; ++r)
        #pragma unroll
        for (int c = 0; c < 4; ++c) acc[r][c] += av[r] * bv[c];
    }
    __syncthreads();
  }

  #pragma unroll
  for (int r = 0; r < 4; ++r) {
    int m = m0 + tm * 4 + r;
    int f0 = n0 + tn * 4;
    float* dst;
    if (mode == 0) {
      dst = &Cp[(size_t)m * N + f0];
    } else {
      int b = m / L_SEQ, l = m % L_SEQ;
      int h = f0 >> 6, d = f0 & 63;
      dst = &Cp[((size_t)(b * NHEAD + h) * L_SEQ + l) * HD + d];
    }
    atomicAdd(dst + 0, acc[r][0]);
    atomicAdd(dst + 1, acc[r][1]);
    atomicAdd(dst + 2, acc[r][2]);
    atomicAdd(dst + 3, acc[r][3]);
  }
}

// ---------------------------------------------------------------------------
// Fused pairwise core v3.
// Grid (JSPLIT=12, 6, 16), block 256 = 64 i x 4 atom-groups; 32 j per block.
// __launch_bounds__(256, 4): 128-VGPR cap -> ~95-VGPR kernel fits SPILL-FREE
// (round-2 lesson: (256,6) forced 40 VGPRs -> 1.3 GB scratch spill traffic).
// ---------------------------------------------------------------------------
__global__ __launch_bounds__(256, 4) void berry_main(
    const float* __restrict__ Q, const float* __restrict__ K,
    const float* __restrict__ V, const float* __restrict__ dde_w,
    const float* __restrict__ dde_b, float* __restrict__ CTXS)
{
  __shared__ float kt[JTILE][HD];
  __shared__ float vt[JTILE][HD];
  __shared__ float ivk[JTILE][16];

  const int tid = threadIdx.x;
  const int bh = blockIdx.z;
  const int i = blockIdx.y * 64 + (tid >> 2);
  const int ag = tid & 3;
  const int js = blockIdx.x;
  const int j0 = js * JTILE;

  // gate params in SGPRs; mean over 16 atoms folded into weights
  float gw[16];
  #pragma unroll
  for (int t = 0; t < 16; ++t) gw[t] = uniform_f(dde_w[t]) * 0.0625f;
  const float gb0 = uniform_f(dde_b[0]), gb1 = uniform_f(dde_b[1]);
  const float gb2 = uniform_f(dde_b[2]), gb3 = uniform_f(dde_b[3]);

  float4 qa[4], ctx[4];
  float ivq[4];
  const float* qp = Q + ((size_t)(bh * L_SEQ + i) * HD + ag * 16);
  #pragma unroll
  for (int t = 0; t < 4; ++t) {
    qa[t] = ((const float4*)qp)[t];
    float d = qa[t].x * qa[t].x + qa[t].y * qa[t].y +
              qa[t].z * qa[t].z + qa[t].w * qa[t].w;
    ivq[t] = __builtin_amdgcn_rsqf(fmaxf(d, 1e-30f));
    ctx[t] = make_float4(0.f, 0.f, 0.f, 0.f);
  }

  // stage K/V tile (32 j x 64 floats each)
  #pragma unroll
  for (int p = 0; p < 2; ++p) {
    int idx = tid + p * 256;           // 0..511 = 32 j x 16 float4
    int jj = idx >> 4, fq = (idx & 15) * 4;
    size_t g = (size_t)(bh * L_SEQ + j0 + jj) * HD + fq;
    *(float4*)&kt[jj][fq] = *(const float4*)(K + g);
    *(float4*)&vt[jj][fq] = *(const float4*)(V + g);
  }
  __syncthreads();
  // per-(j, atom) inverse k-norms: 512 atoms, 2 per thread
  #pragma unroll
  for (int p = 0; p < 2; ++p) {
    int a = tid + p * 256;
    int jj = a >> 4, at = a & 15;
    float4 kq = *(const float4*)&kt[jj][at * 4];
    float d = kq.x * kq.x + kq.y * kq.y + kq.z * kq.z + kq.w * kq.w;
    ivk[jj][at] = __builtin_amdgcn_rsqf(fmaxf(d, 1e-30f));
  }
  __syncthreads();

  for (int jj = 0; jj < JTILE; ++jj) {
    float4 sp[4];
    float4 ik4 = *(const float4*)&ivk[jj][ag * 4];
    float ikv[4] = {ik4.x, ik4.y, ik4.z, ik4.w};
    float4 gs = make_float4(0.f, 0.f, 0.f, 0.f);
    #pragma unroll
    for (int a = 0; a < 4; ++a) {
      float4 kq = *(const float4*)&kt[jj][ag * 16 + a * 4];
      float inv = ivq[a] * ikv[a];
      float hx = qa[a].x * kq.x - qa[a].y * kq.y - qa[a].z * kq.z - qa[a].w * kq.w;
      float hy = qa[a].x * kq.y + qa[a].y * kq.x + qa[a].z * kq.w - qa[a].w * kq.z;
      float hz = qa[a].x * kq.z - qa[a].y * kq.w + qa[a].z * kq.x + qa[a].w * kq.y;
      float hw = qa[a].x * kq.w + qa[a].y * kq.z - qa[a].z * kq.y + qa[a].w * kq.x;
      sp[a].x = hx * inv; sp[a].y = hy * inv;
      sp[a].z = hz * inv; sp[a].w = hw * inv;
      gs.x += sp[a].x; gs.y += sp[a].y; gs.z += sp[a].z; gs.w += sp[a].w;
    }
    // sum across the 4 atom-group lanes (16 atoms); mean folded into gw
    gs.x += __shfl_xor(gs.x, 1, 64); gs.y += __shfl_xor(gs.y, 1, 64);
    gs.z += __shfl_xor(gs.z, 1, 64); gs.w += __shfl_xor(gs.w, 1, 64);
    gs.x += __shfl_xor(gs.x, 2, 64); gs.y += __shfl_xor(gs.y, 2, 64);
    gs.z += __shfl_xor(gs.z, 2, 64); gs.w += __shfl_xor(gs.w, 2, 64);

    float t0 = gb0 + gw[0]  * gs.x + gw[1]  * gs.y + gw[2]  * gs.z + gw[3]  * gs.w;
    float t1 = gb1 + gw[4]  * gs.x + gw[5]  * gs.y + gw[6]  * gs.z + gw[7]  * gs.w;
    float t2 = gb2 + gw[8]  * gs.x + gw[9]  * gs.y + gw[10] * gs.z + gw[11] * gs.w;
    float t3 = gb3 + gw[12] * gs.x + gw[13] * gs.y + gw[14] * gs.z + gw[15] * gs.w;
    float4 g;
    g.x = __builtin_amdgcn_rcpf(1.f + __expf(-t0));
    g.y = __builtin_amdgcn_rcpf(1.f + __expf(-t1));
    g.z = __builtin_amdgcn_rcpf(1.f + __expf(-t2));
    g.w = __builtin_amdgcn_rcpf(1.f + __expf(-t3));

    #pragma unroll
    for (int a = 0; a < 4; ++a) {
      float4 vq = *(const float4*)&vt[jj][ag * 16 + a * 4];
      float sx = sp[a].x * g.x, sy = sp[a].y * g.y;
      float sz = sp[a].z * g.z, sw = sp[a].w * g.w;
      ctx[a].x += sx * vq.x - sy * vq.y - sz * vq.z - sw * vq.w;
      ctx[a].y += sx * vq.y + sy * vq.x + sz * vq.w - sw * vq.z;
      ctx[a].z += sx * vq.z - sy * vq.w + sz * vq.x + sw * vq.y;
      ctx[a].w += sx * vq.w + sy * vq.z - sz * vq.y + sw * vq.x;
    }
  }

  // plain stores into this j-chunk's slab
  float* cp = CTXS + ((size_t)(js * NBH + bh) * L_SEQ + i) * HD + ag * 16;
  #pragma unroll
  for (int t = 0; t < 4; ++t) ((float4*)cp)[t] = ctx[t];
}

// ---------------------------------------------------------------------------
// Sum the JSPLIT ctx slabs and transpose heads into (b, l, e) layout.
// ---------------------------------------------------------------------------
__global__ __launch_bounds__(256) void ctx_reduce(
    const float* __restrict__ CTXS, float* __restrict__ CTX)
{
  int idx = blockIdx.x * 256 + threadIdx.x;      // over 98304 float4 groups
  int row = idx >> 4;                            // bh*L + i
  int d0 = (idx & 15) * 4;
  float4 s = make_float4(0.f, 0.f, 0.f, 0.f);
  #pragma unroll
  for (int js = 0; js < JSPLIT; ++js) {
    float4 v = *(const float4*)&CTXS[(size_t)js * PROJ_ELEMS + (size_t)row * HD + d0];
    s.x += v.x; s.y += v.y; s.z += v.z; s.w += v.w;
  }
  int bh = row / L_SEQ, i = row - bh * L_SEQ;
  int b = bh >> 3, h = bh & 7;
  *(float4*)&CTX[((size_t)(b * L_SEQ + i) * E_DIM) + h * HD + d0] = s;
}

// ---------------------------------------------------------------------------
extern "C" void kernel_launch(void* const* d_in, const int* in_sizes, int n_in,
                              void* d_out, int out_size, void* d_ws, size_t ws_size,
                              hipStream_t stream)
{
  const float* x     = (const float*)d_in[0];
  const float* Wq    = (const float*)d_in[1];
  const float* Wk    = (const float*)d_in[2];
  const float* Wv    = (const float*)d_in[3];
  const float* Wo    = (const float*)d_in[4];
  const float* dde_w = (const float*)d_in[5];
  const float* dde_b = (const float*)d_in[6];
  float* out = (float*)d_out;

  float* Qw   = (float*)d_ws;
  float* Kw   = Qw + PROJ_ELEMS;
  float* Vw   = Kw + PROJ_ELEMS;
  float* CTX  = Vw + PROJ_ELEMS;
  float* CTXS = CTX + PROJ_ELEMS;                // JSPLIT slabs

  // zero atomic-accumulated outputs (Qw/Kw/Vw contiguous) and d_out
  hipMemsetAsync(Qw, 0, (size_t)3 * PROJ_ELEMS * sizeof(float), stream);
  hipMemsetAsync(out, 0, (size_t)2 * L_SEQ * E_DIM * sizeof(float), stream);

  // Q/K/V projections: split-K=4, head-scatter epilogue
  dim3 gp(E_DIM / 64, (2 * L_SEQ) / 64, 3 * 4);
  gemm_abt_splitk<<<gp, 256, 0, stream>>>(x, Wq, Wk, Wv, Qw, Kw, Vw,
                                          2 * L_SEQ, E_DIM, E_DIM, 128, 4, 1);

  // fused pairwise core
  dim3 gm(JSPLIT, 6, NBH);
  berry_main<<<gm, 256, 0, stream>>>(Qw, Kw, Vw, dde_w, dde_b, CTXS);

  // slab reduction + head transpose
  ctx_reduce<<<384, 256, 0, stream>>>(CTXS, CTX);

  // output projection: split-K=4
  dim3 go(E_DIM / 64, (2 * L_SEQ) / 64, 4);
  gemm_abt_splitk<<<go, 256, 0, stream>>>(CTX, Wo, nullptr, nullptr, out, nullptr, nullptr,
                                          2 * L_SEQ, E_DIM, E_DIM, 128, 4, 0);
}

// Round 4
// 214.879 us; speedup vs baseline: 2.3444x; 1.1732x over previous
//
#include <hip/hip_runtime.h>
#include <math.h>

#define L_SEQ 384
#define E_DIM 512
#define NHEAD 8
#define NBH   16
#define HD    64
#define JSPLIT 12
#define JTILE  32          // L_SEQ / JSPLIT
#define PROJ_ELEMS (NBH * L_SEQ * HD)   // 393216

__device__ __forceinline__ float uniform_f(float v) {
  return __uint_as_float(__builtin_amdgcn_readfirstlane(__float_as_uint(v)));
}

// ---------------------------------------------------------------------------
// GEMM: C = A @ B^T, plain stores, NO split-K, NO atomics (round-3 lesson:
// atomic epilogues serialized at L2 and dominated the non-berry 162 us).
// A: MxK row-major, Bm: NxK row-major. Tile 32(m) x 64(n), BK=16, 256 thr,
// 2x4 outputs/thread. grid.z picks among B0/B1/B2 + output buffer.
// mode 0: C[m*N + f]; mode 1: head-scatter C[((b*8+h)*L + l)*64 + d].
// ---------------------------------------------------------------------------
__global__ __launch_bounds__(256) void gemm_abt(
    const float* __restrict__ A, const float* __restrict__ B0,
    const float* __restrict__ B1, const float* __restrict__ B2,
    float* __restrict__ C0, float* __restrict__ C1, float* __restrict__ C2,
    int M, int N, int K, int mode)
{
  __shared__ float As[16][34];   // [k][m], 34 keeps float2 alignment, banks ok
  __shared__ float Bs[16][68];   // [k][n]

  const int tid = threadIdx.x;
  const int z = blockIdx.z;
  const float* Bm = (z == 0) ? B0 : (z == 1) ? B1 : B2;
  float* Cp = (z == 0) ? C0 : (z == 1) ? C1 : C2;

  const int m0 = blockIdx.y * 32;
  const int n0 = blockIdx.x * 64;
  const int tm = tid >> 4;    // 0..15 -> rows tm*2, tm*2+1
  const int tn = tid & 15;    // 0..15 -> cols tn*4..tn*4+3

  float acc[2][4];
  #pragma unroll
  for (int r = 0; r < 2; ++r)
    #pragma unroll
    for (int c = 0; c < 4; ++c) acc[r][c] = 0.f;

  for (int k0 = 0; k0 < K; k0 += 16) {
    #pragma unroll
    for (int p = 0; p < 2; ++p) {           // As: 32x16 = 512 elems
      int idx = tid + p * 256;
      int row = idx >> 4, col = idx & 15;
      As[col][row] = A[(size_t)(m0 + row) * K + k0 + col];
    }
    #pragma unroll
    for (int p = 0; p < 4; ++p) {           // Bs: 64x16 = 1024 elems
      int idx = tid + p * 256;
      int row = idx >> 4, col = idx & 15;
      Bs[col][row] = Bm[(size_t)(n0 + row) * K + k0 + col];
    }
    __syncthreads();
    #pragma unroll
    for (int kk = 0; kk < 16; ++kk) {
      float2 a = *(const float2*)&As[kk][tm * 2];
      float4 b = *(const float4*)&Bs[kk][tn * 4];
      acc[0][0] += a.x * b.x; acc[0][1] += a.x * b.y;
      acc[0][2] += a.x * b.z; acc[0][3] += a.x * b.w;
      acc[1][0] += a.y * b.x; acc[1][1] += a.y * b.y;
      acc[1][2] += a.y * b.z; acc[1][3] += a.y * b.w;
    }
    __syncthreads();
  }

  #pragma unroll
  for (int r = 0; r < 2; ++r) {
    int m = m0 + tm * 2 + r;
    int f0 = n0 + tn * 4;
    float4 val = make_float4(acc[r][0], acc[r][1], acc[r][2], acc[r][3]);
    if (mode == 0) {
      *(float4*)&Cp[(size_t)m * N + f0] = val;
    } else {
      int b = m / L_SEQ, l = m % L_SEQ;
      int h = f0 >> 6, d = f0 & 63;
      *(float4*)&Cp[((size_t)(b * NHEAD + h) * L_SEQ + l) * HD + d] = val;
    }
  }
}

// ---------------------------------------------------------------------------
// Fused pairwise core v4.
// Algebra: spinor = ham(q,k)/(|q||k|) = ham(q_hat, k_hat) -> normalize q at
// load and k at staging; NO per-pair normalization in the inner loop.
// Block = 32 i x 8 atom-groups (2 atoms/thread); grid (12, 12, 16) = 2304
// blocks ~ 9 blocks/CU for latency hiding. Gate reduce = shuffle xor 1,2,4.
// ---------------------------------------------------------------------------
__device__ __forceinline__ float4 hamilton(float4 a, float4 b) {
  float4 r;
  r.x = a.x * b.x - a.y * b.y - a.z * b.z - a.w * b.w;
  r.y = a.x * b.y + a.y * b.x + a.z * b.w - a.w * b.z;
  r.z = a.x * b.z - a.y * b.w + a.z * b.x + a.w * b.y;
  r.w = a.x * b.w + a.y * b.z - a.z * b.y + a.w * b.x;
  return r;
}

__global__ __launch_bounds__(256, 4) void berry_main(
    const float* __restrict__ Q, const float* __restrict__ K,
    const float* __restrict__ V, const float* __restrict__ dde_w,
    const float* __restrict__ dde_b, float* __restrict__ CTXS)
{
  __shared__ float kt[JTILE][HD];   // normalized k atoms
  __shared__ float vt[JTILE][HD];   // raw v

  const int tid = threadIdx.x;
  const int bh = blockIdx.z;
  const int i = blockIdx.y * 32 + (tid >> 3);
  const int ag = tid & 7;                 // owns atoms ag*2, ag*2+1
  const int js = blockIdx.x;
  const int j0 = js * JTILE;

  // gate params in SGPRs; mean over 16 atoms folded into weights
  float gw[16];
  #pragma unroll
  for (int t = 0; t < 16; ++t) gw[t] = uniform_f(dde_w[t]) * 0.0625f;
  const float gb0 = uniform_f(dde_b[0]), gb1 = uniform_f(dde_b[1]);
  const float gb2 = uniform_f(dde_b[2]), gb3 = uniform_f(dde_b[3]);

  float4 qa[2], ctx[2];
  const float* qp = Q + ((size_t)(bh * L_SEQ + i) * HD + ag * 8);
  #pragma unroll
  for (int t = 0; t < 2; ++t) {
    float4 q = ((const float4*)qp)[t];
    float d = q.x * q.x + q.y * q.y + q.z * q.z + q.w * q.w;
    float r = __builtin_amdgcn_rsqf(fmaxf(d, 1e-30f));
    qa[t].x = q.x * r; qa[t].y = q.y * r; qa[t].z = q.z * r; qa[t].w = q.w * r;
    ctx[t] = make_float4(0.f, 0.f, 0.f, 0.f);
  }

  // stage K (normalized per atom) + V: 32 j x 16 atoms = 512, 2/thread
  #pragma unroll
  for (int p = 0; p < 2; ++p) {
    int idx = tid + p * 256;
    int jj = idx >> 4, at = idx & 15;
    size_t g = (size_t)(bh * L_SEQ + j0 + jj) * HD + at * 4;
    float4 kq = *(const float4*)(K + g);
    float d = kq.x * kq.x + kq.y * kq.y + kq.z * kq.z + kq.w * kq.w;
    float r = __builtin_amdgcn_rsqf(fmaxf(d, 1e-30f));
    kq.x *= r; kq.y *= r; kq.z *= r; kq.w *= r;
    *(float4*)&kt[jj][at * 4] = kq;
    *(float4*)&vt[jj][at * 4] = *(const float4*)(V + g);
  }
  __syncthreads();

  for (int jj = 0; jj < JTILE; ++jj) {
    float4 k0 = *(const float4*)&kt[jj][ag * 8];
    float4 k1 = *(const float4*)&kt[jj][ag * 8 + 4];
    float4 h0 = hamilton(qa[0], k0);       // already unit spinors
    float4 h1 = hamilton(qa[1], k1);

    float gsx = h0.x + h1.x, gsy = h0.y + h1.y;
    float gsz = h0.z + h1.z, gsw = h0.w + h1.w;
    // sum across the 8 lanes of this i (16 atoms); mean folded into gw
    gsx += __shfl_xor(gsx, 1, 64); gsy += __shfl_xor(gsy, 1, 64);
    gsz += __shfl_xor(gsz, 1, 64); gsw += __shfl_xor(gsw, 1, 64);
    gsx += __shfl_xor(gsx, 2, 64); gsy += __shfl_xor(gsy, 2, 64);
    gsz += __shfl_xor(gsz, 2, 64); gsw += __shfl_xor(gsw, 2, 64);
    gsx += __shfl_xor(gsx, 4, 64); gsy += __shfl_xor(gsy, 4, 64);
    gsz += __shfl_xor(gsz, 4, 64); gsw += __shfl_xor(gsw, 4, 64);

    float t0 = gb0 + gw[0]  * gsx + gw[1]  * gsy + gw[2]  * gsz + gw[3]  * gsw;
    float t1 = gb1 + gw[4]  * gsx + gw[5]  * gsy + gw[6]  * gsz + gw[7]  * gsw;
    float t2 = gb2 + gw[8]  * gsx + gw[9]  * gsy + gw[10] * gsz + gw[11] * gsw;
    float t3 = gb3 + gw[12] * gsx + gw[13] * gsy + gw[14] * gsz + gw[15] * gsw;
    float4 g;
    g.x = __builtin_amdgcn_rcpf(1.f + __expf(-t0));
    g.y = __builtin_amdgcn_rcpf(1.f + __expf(-t1));
    g.z = __builtin_amdgcn_rcpf(1.f + __expf(-t2));
    g.w = __builtin_amdgcn_rcpf(1.f + __expf(-t3));

    float4 v0 = *(const float4*)&vt[jj][ag * 8];
    float4 v1 = *(const float4*)&vt[jj][ag * 8 + 4];
    {
      float sx = h0.x * g.x, sy = h0.y * g.y, sz = h0.z * g.z, sw = h0.w * g.w;
      ctx[0].x += sx * v0.x - sy * v0.y - sz * v0.z - sw * v0.w;
      ctx[0].y += sx * v0.y + sy * v0.x + sz * v0.w - sw * v0.z;
      ctx[0].z += sx * v0.z - sy * v0.w + sz * v0.x + sw * v0.y;
      ctx[0].w += sx * v0.w + sy * v0.z - sz * v0.y + sw * v0.x;
    }
    {
      float sx = h1.x * g.x, sy = h1.y * g.y, sz = h1.z * g.z, sw = h1.w * g.w;
      ctx[1].x += sx * v1.x - sy * v1.y - sz * v1.z - sw * v1.w;
      ctx[1].y += sx * v1.y + sy * v1.x + sz * v1.w - sw * v1.z;
      ctx[1].z += sx * v1.z - sy * v1.w + sz * v1.x + sw * v1.y;
      ctx[1].w += sx * v1.w + sy * v1.z - sz * v1.y + sw * v1.x;
    }
  }

  // plain stores into this j-chunk's slab
  float* cp = CTXS + ((size_t)(js * NBH + bh) * L_SEQ + i) * HD + ag * 8;
  ((float4*)cp)[0] = ctx[0];
  ((float4*)cp)[1] = ctx[1];
}

// ---------------------------------------------------------------------------
// Sum the JSPLIT ctx slabs and transpose heads into (b, l, e) layout.
// ---------------------------------------------------------------------------
__global__ __launch_bounds__(256) void ctx_reduce(
    const float* __restrict__ CTXS, float* __restrict__ CTX)
{
  int idx = blockIdx.x * 256 + threadIdx.x;      // over 98304 float4 groups
  int row = idx >> 4;                            // bh*L + i
  int d0 = (idx & 15) * 4;
  float4 s = make_float4(0.f, 0.f, 0.f, 0.f);
  #pragma unroll
  for (int js = 0; js < JSPLIT; ++js) {
    float4 v = *(const float4*)&CTXS[(size_t)js * PROJ_ELEMS + (size_t)row * HD + d0];
    s.x += v.x; s.y += v.y; s.z += v.z; s.w += v.w;
  }
  int bh = row / L_SEQ, i = row - bh * L_SEQ;
  int b = bh >> 3, h = bh & 7;
  *(float4*)&CTX[((size_t)(b * L_SEQ + i) * E_DIM) + h * HD + d0] = s;
}

// ---------------------------------------------------------------------------
extern "C" void kernel_launch(void* const* d_in, const int* in_sizes, int n_in,
                              void* d_out, int out_size, void* d_ws, size_t ws_size,
                              hipStream_t stream)
{
  const float* x     = (const float*)d_in[0];
  const float* Wq    = (const float*)d_in[1];
  const float* Wk    = (const float*)d_in[2];
  const float* Wv    = (const float*)d_in[3];
  const float* Wo    = (const float*)d_in[4];
  const float* dde_w = (const float*)d_in[5];
  const float* dde_b = (const float*)d_in[6];
  float* out = (float*)d_out;

  float* Qw   = (float*)d_ws;
  float* Kw   = Qw + PROJ_ELEMS;
  float* Vw   = Kw + PROJ_ELEMS;
  float* CTX  = Vw + PROJ_ELEMS;
  float* CTXS = CTX + PROJ_ELEMS;                // JSPLIT slabs

  // Q/K/V projections: plain stores, head-scatter epilogue (no memset needed)
  dim3 gp(E_DIM / 64, (2 * L_SEQ) / 32, 3);
  gemm_abt<<<gp, 256, 0, stream>>>(x, Wq, Wk, Wv, Qw, Kw, Vw,
                                   2 * L_SEQ, E_DIM, E_DIM, 1);

  // fused pairwise core
  dim3 gm(JSPLIT, 12, NBH);
  berry_main<<<gm, 256, 0, stream>>>(Qw, Kw, Vw, dde_w, dde_b, CTXS);

  // slab reduction + head transpose
  ctx_reduce<<<384, 256, 0, stream>>>(CTXS, CTX);

  // output projection: plain stores
  dim3 go(E_DIM / 64, (2 * L_SEQ) / 32, 1);
  gemm_abt<<<go, 256, 0, stream>>>(CTX, Wo, nullptr, nullptr, out, nullptr, nullptr,
                                   2 * L_SEQ, E_DIM, E_DIM, 0);
}

// Round 5
// 178.363 us; speedup vs baseline: 2.8244x; 1.2047x over previous
//
#include <hip/hip_runtime.h>
#include <math.h>

#define L_SEQ 384
#define E_DIM 512
#define NHEAD 8
#define NBH   16
#define HD    64
#define JSPLIT 12
#define JTILE  32          // L_SEQ / JSPLIT
#define PROJ_ELEMS (NBH * L_SEQ * HD)   // 393216

typedef __attribute__((ext_vector_type(8))) __bf16 bf16x8;
typedef __attribute__((ext_vector_type(4))) float f32x4;

__device__ __forceinline__ float uniform_f(float v) {
  return __uint_as_float(__builtin_amdgcn_readfirstlane(__float_as_uint(v)));
}

__device__ __forceinline__ unsigned f2bf(float f) {   // RNE float->bf16 bits
  unsigned u = __float_as_uint(f);
  return (u + 0x7FFFu + ((u >> 16) & 1u)) >> 16;
}

// sum over the 4 lanes of each quad — pure-VALU DPP quad_perm butterfly
// (replaces ds_swizzle shuffles: no LDS pipe, no lgkm latency chains)
__device__ __forceinline__ float quad_sum(float x) {
  x += __int_as_float(__builtin_amdgcn_mov_dpp(__float_as_int(x), 0xB1, 0xF, 0xF, 0)); // xor 1
  x += __int_as_float(__builtin_amdgcn_mov_dpp(__float_as_int(x), 0x4E, 0xF, 0xF, 0)); // xor 2
  return x;
}

// ---------------------------------------------------------------------------
// Convert x|Wq|Wk|Wv (contiguous dst1) and Wo (dst2) to bf16.
// 1,441,792 elems, 4/thread, grid 1408x256 exact.
// ---------------------------------------------------------------------------
__global__ __launch_bounds__(256) void to_bf16_all(
    const float* __restrict__ x, const float* __restrict__ Wq,
    const float* __restrict__ Wk, const float* __restrict__ Wv,
    const float* __restrict__ Wo, unsigned short* __restrict__ dst1,
    unsigned short* __restrict__ dst2)
{
  int e0 = (blockIdx.x * 256 + threadIdx.x) * 4;
  if (e0 >= 1441792) return;
  const float* src; unsigned short* d; int s;
  if (e0 < 393216)       { src = x;  s = e0;           d = dst1 + e0; }
  else if (e0 < 655360)  { src = Wq; s = e0 - 393216;  d = dst1 + e0; }
  else if (e0 < 917504)  { src = Wk; s = e0 - 655360;  d = dst1 + e0; }
  else if (e0 < 1179648) { src = Wv; s = e0 - 917504;  d = dst1 + e0; }
  else                   { src = Wo; s = e0 - 1179648; d = dst2 + s;  }
  float4 v = *(const float4*)(src + s);
  unsigned lo = f2bf(v.x) | (f2bf(v.y) << 16);
  unsigned hi = f2bf(v.z) | (f2bf(v.w) << 16);
  *(uint2*)d = make_uint2(lo, hi);
}

// ---------------------------------------------------------------------------
// bf16 MFMA GEMM: C = A @ B^T.  A: MxK bf16 row-major, Bm: NxK bf16 row-major.
// No LDS staging: inputs are L2-resident (<3 MB); direct 16B frag loads.
// Block 256 = 4 waves; block tile 64(m)x64(n); wave = 16-row m-strip,
// 4 n-tiles of 16; K-loop step 32 -> 4 MFMAs/step, 16 steps.
// A-frag: A[m=lane&15][k = quad*8 + j]; b-frag same pattern on B rows (A@B^T).
// D: row(m)=quad*4+reg, col(n)=lane&15  [m89-verified layout].
// mode 0: C[m*N+f]; mode 1: head-scatter C[((b*8+h)*L+l)*64+d].
// ---------------------------------------------------------------------------
__global__ __launch_bounds__(256) void gemm_mfma(
    const __bf16* __restrict__ A, const __bf16* __restrict__ B0,
    const __bf16* __restrict__ B1, const __bf16* __restrict__ B2,
    float* __restrict__ C0, float* __restrict__ C1, float* __restrict__ C2,
    int M, int N, int K, int mode)
{
  const int z = blockIdx.z;
  const __bf16* Bm = (z == 0) ? B0 : (z == 1) ? B1 : B2;
  float* Cp = (z == 0) ? C0 : (z == 1) ? C1 : C2;

  const int tid = threadIdx.x;
  const int wave = tid >> 6, lane = tid & 63;
  const int m0 = blockIdx.y * 64 + wave * 16;
  const int n0 = blockIdx.x * 64;
  const int mr = lane & 15, quad = lane >> 4;

  f32x4 acc[4];
  #pragma unroll
  for (int nt = 0; nt < 4; ++nt) acc[nt] = (f32x4){0.f, 0.f, 0.f, 0.f};

  const __bf16* ap = A + (size_t)(m0 + mr) * K + quad * 8;
  const __bf16* bp = Bm + (size_t)(n0 + mr) * K + quad * 8;

  #pragma unroll 4
  for (int k0 = 0; k0 < K; k0 += 32) {
    bf16x8 a = *(const bf16x8*)(ap + k0);
    #pragma unroll
    for (int nt = 0; nt < 4; ++nt) {
      bf16x8 b = *(const bf16x8*)(bp + (size_t)nt * 16 * K + k0);
      acc[nt] = __builtin_amdgcn_mfma_f32_16x16x32_bf16(a, b, acc[nt], 0, 0, 0);
    }
  }

  #pragma unroll
  for (int nt = 0; nt < 4; ++nt) {
    int n = n0 + nt * 16 + mr;
    #pragma unroll
    for (int r = 0; r < 4; ++r) {
      int m = m0 + quad * 4 + r;
      if (mode == 0) {
        Cp[(size_t)m * N + n] = acc[nt][r];
      } else {
        int b = m / L_SEQ, l = m % L_SEQ;
        int h = n >> 6, d = n & 63;
        Cp[((size_t)(b * NHEAD + h) * L_SEQ + l) * HD + d] = acc[nt][r];
      }
    }
  }
}

// ---------------------------------------------------------------------------
// Fused pairwise core v5.
// Block 128 = 32 i x 4 lanes (quad-aligned), 4 atoms/thread.
// Gate reduce = DPP quad_perm (no LDS swizzle, no shuffle latency chains);
// sigmoid redundancy = 4 lanes (was 8). Prenormalized q/k (|ham(q,k)|=|q||k|).
// Grid (12, 12, 16) = 2304 blocks.
// ---------------------------------------------------------------------------
__global__ __launch_bounds__(128, 4) void berry_main(
    const float* __restrict__ Q, const float* __restrict__ K,
    const float* __restrict__ V, const float* __restrict__ dde_w,
    const float* __restrict__ dde_b, float* __restrict__ CTXS)
{
  __shared__ float kt[JTILE][HD];   // normalized k atoms
  __shared__ float vt[JTILE][HD];   // raw v

  const int tid = threadIdx.x;
  const int bh = blockIdx.z;
  const int i = blockIdx.y * 32 + (tid >> 2);
  const int ag = tid & 3;                 // lane-in-quad: atoms ag*4 .. ag*4+3
  const int js = blockIdx.x;
  const int j0 = js * JTILE;

  // gate params in SGPRs; mean over 16 atoms folded into weights
  float gw[16];
  #pragma unroll
  for (int t = 0; t < 16; ++t) gw[t] = uniform_f(dde_w[t]) * 0.0625f;
  const float gb0 = uniform_f(dde_b[0]), gb1 = uniform_f(dde_b[1]);
  const float gb2 = uniform_f(dde_b[2]), gb3 = uniform_f(dde_b[3]);

  float4 qa[4], ctx[4];
  const float* qp = Q + ((size_t)(bh * L_SEQ + i) * HD + ag * 16);
  #pragma unroll
  for (int t = 0; t < 4; ++t) {
    float4 q = ((const float4*)qp)[t];
    float d = q.x * q.x + q.y * q.y + q.z * q.z + q.w * q.w;
    float r = __builtin_amdgcn_rsqf(fmaxf(d, 1e-30f));
    qa[t].x = q.x * r; qa[t].y = q.y * r; qa[t].z = q.z * r; qa[t].w = q.w * r;
    ctx[t] = make_float4(0.f, 0.f, 0.f, 0.f);
  }

  // stage K (normalized per atom) + V: 32 j x 16 atoms = 512, 4/thread
  #pragma unroll
  for (int p = 0; p < 4; ++p) {
    int idx = tid + p * 128;
    int jj = idx >> 4, at = idx & 15;
    size_t g = (size_t)(bh * L_SEQ + j0 + jj) * HD + at * 4;
    float4 kq = *(const float4*)(K + g);
    float d = kq.x * kq.x + kq.y * kq.y + kq.z * kq.z + kq.w * kq.w;
    float r = __builtin_amdgcn_rsqf(fmaxf(d, 1e-30f));
    kq.x *= r; kq.y *= r; kq.z *= r; kq.w *= r;
    *(float4*)&kt[jj][at * 4] = kq;
    *(float4*)&vt[jj][at * 4] = *(const float4*)(V + g);
  }
  __syncthreads();

  for (int jj = 0; jj < JTILE; ++jj) {
    float4 h[4];
    float gsx = 0.f, gsy = 0.f, gsz = 0.f, gsw = 0.f;
    #pragma unroll
    for (int a = 0; a < 4; ++a) {
      float4 kq = *(const float4*)&kt[jj][ag * 16 + a * 4];
      h[a].x = qa[a].x * kq.x - qa[a].y * kq.y - qa[a].z * kq.z - qa[a].w * kq.w;
      h[a].y = qa[a].x * kq.y + qa[a].y * kq.x + qa[a].z * kq.w - qa[a].w * kq.z;
      h[a].z = qa[a].x * kq.z - qa[a].y * kq.w + qa[a].z * kq.x + qa[a].w * kq.y;
      h[a].w = qa[a].x * kq.w + qa[a].y * kq.z - qa[a].z * kq.y + qa[a].w * kq.x;
      gsx += h[a].x; gsy += h[a].y; gsz += h[a].z; gsw += h[a].w;
    }
    // 16-atom sums via DPP quad butterflies (VALU-rate, no LDS)
    gsx = quad_sum(gsx); gsy = quad_sum(gsy);
    gsz = quad_sum(gsz); gsw = quad_sum(gsw);

    float t0 = gb0 + gw[0]  * gsx + gw[1]  * gsy + gw[2]  * gsz + gw[3]  * gsw;
    float t1 = gb1 + gw[4]  * gsx + gw[5]  * gsy + gw[6]  * gsz + gw[7]  * gsw;
    float t2 = gb2 + gw[8]  * gsx + gw[9]  * gsy + gw[10] * gsz + gw[11] * gsw;
    float t3 = gb3 + gw[12] * gsx + gw[13] * gsy + gw[14] * gsz + gw[15] * gsw;
    float4 g;
    g.x = __builtin_amdgcn_rcpf(1.f + __expf(-t0));
    g.y = __builtin_amdgcn_rcpf(1.f + __expf(-t1));
    g.z = __builtin_amdgcn_rcpf(1.f + __expf(-t2));
    g.w = __builtin_amdgcn_rcpf(1.f + __expf(-t3));

    #pragma unroll
    for (int a = 0; a < 4; ++a) {
      float4 vq = *(const float4*)&vt[jj][ag * 16 + a * 4];
      float sx = h[a].x * g.x, sy = h[a].y * g.y;
      float sz = h[a].z * g.z, sw = h[a].w * g.w;
      ctx[a].x += sx * vq.x - sy * vq.y - sz * vq.z - sw * vq.w;
      ctx[a].y += sx * vq.y + sy * vq.x + sz * vq.w - sw * vq.z;
      ctx[a].z += sx * vq.z - sy * vq.w + sz * vq.x + sw * vq.y;
      ctx[a].w += sx * vq.w + sy * vq.z - sz * vq.y + sw * vq.x;
    }
  }

  // plain stores into this j-chunk's slab (coalesced: quad covers 64 floats)
  float* cp = CTXS + ((size_t)(js * NBH + bh) * L_SEQ + i) * HD + ag * 16;
  #pragma unroll
  for (int t = 0; t < 4; ++t) ((float4*)cp)[t] = ctx[t];
}

// ---------------------------------------------------------------------------
// Sum the JSPLIT ctx slabs, transpose heads into (b,l,e), emit bf16 for
// the MFMA output projection.
// ---------------------------------------------------------------------------
__global__ __launch_bounds__(256) void ctx_reduce(
    const float* __restrict__ CTXS, unsigned short* __restrict__ CTXB)
{
  int idx = blockIdx.x * 256 + threadIdx.x;      // over 98304 float4 groups
  int row = idx >> 4;                            // bh*L + i
  int d0 = (idx & 15) * 4;
  float4 s = make_float4(0.f, 0.f, 0.f, 0.f);
  #pragma unroll
  for (int js = 0; js < JSPLIT; ++js) {
    float4 v = *(const float4*)&CTXS[(size_t)js * PROJ_ELEMS + (size_t)row * HD + d0];
    s.x += v.x; s.y += v.y; s.z += v.z; s.w += v.w;
  }
  int bh = row / L_SEQ, i = row - bh * L_SEQ;
  int b = bh >> 3, h = bh & 7;
  unsigned lo = f2bf(s.x) | (f2bf(s.y) << 16);
  unsigned hi = f2bf(s.z) | (f2bf(s.w) << 16);
  *(uint2*)&CTXB[((size_t)(b * L_SEQ + i) * E_DIM) + h * HD + d0] = make_uint2(lo, hi);
}

// ---------------------------------------------------------------------------
// Workspace layout (lifetime-overlaid, total 24,117,248 B < proven 25.2 MB):
//   [0          .. 1572864)  Qw fp32            | CTXB bf16 (after berry)
//   [1572864    .. 3145728)  Kw fp32
//   [3145728    .. 4718592)  Vw fp32
//   [4718592    .. 23592960) CTXS (12 slabs)    | xb|Wqb|Wkb|Wvb bf16 (before berry)
//   [23592960   .. 24117248) Wob bf16 (lives to the end)
// ---------------------------------------------------------------------------
extern "C" void kernel_launch(void* const* d_in, const int* in_sizes, int n_in,
                              void* d_out, int out_size, void* d_ws, size_t ws_size,
                              hipStream_t stream)
{
  const float* x     = (const float*)d_in[0];
  const float* Wq    = (const float*)d_in[1];
  const float* Wk    = (const float*)d_in[2];
  const float* Wv    = (const float*)d_in[3];
  const float* Wo    = (const float*)d_in[4];
  const float* dde_w = (const float*)d_in[5];
  const float* dde_b = (const float*)d_in[6];
  float* out = (float*)d_out;

  char* ws = (char*)d_ws;
  float* Qw   = (float*)(ws + 0);
  float* Kw   = (float*)(ws + 1572864);
  float* Vw   = (float*)(ws + 3145728);
  float* CTXS = (float*)(ws + 4718592);
  unsigned short* xb   = (unsigned short*)(ws + 4718592);   // dead before berry writes CTXS
  unsigned short* Wqb  = (unsigned short*)(ws + 5505024);
  unsigned short* Wkb  = (unsigned short*)(ws + 6029312);
  unsigned short* Wvb  = (unsigned short*)(ws + 6553600);
  unsigned short* Wob  = (unsigned short*)(ws + 23592960);
  unsigned short* CTXB = (unsigned short*)(ws + 0);         // born after Qw is dead

  // 1) fp32 -> bf16 conversions (x|Wq|Wk|Wv contiguous, Wo separate)
  to_bf16_all<<<1408, 256, 0, stream>>>(x, Wq, Wk, Wv, Wo, xb, Wob);

  // 2) Q/K/V projections: bf16 MFMA, head-scatter fp32 epilogue
  gemm_mfma<<<dim3(8, 12, 3), 256, 0, stream>>>(
      (const __bf16*)xb, (const __bf16*)Wqb, (const __bf16*)Wkb, (const __bf16*)Wvb,
      Qw, Kw, Vw, 2 * L_SEQ, E_DIM, E_DIM, 1);

  // 3) fused pairwise core
  berry_main<<<dim3(JSPLIT, 12, NBH), 128, 0, stream>>>(Qw, Kw, Vw, dde_w, dde_b, CTXS);

  // 4) slab reduction + head transpose -> bf16
  ctx_reduce<<<384, 256, 0, stream>>>(CTXS, CTXB);

  // 5) output projection: bf16 MFMA, fp32 out
  gemm_mfma<<<dim3(8, 12, 1), 256, 0, stream>>>(
      (const __bf16*)CTXB, (const __bf16*)Wob, nullptr, nullptr,
      out, nullptr, nullptr, 2 * L_SEQ, E_DIM, E_DIM, 0);
}